// Round 1
// 152.223 us; speedup vs baseline: 1.0780x; 1.0780x over previous
//
#include <hip/hip_runtime.h>

#define IN_F 256
#define OUT_F 4096
#define BATCH 8192
#define B_PER_BLOCK 16   // batch rows per block; grid.y = 512 -> 2048 blocks

typedef float v4f __attribute__((ext_vector_type(4)));

// Kernel 1: recover the one-hot source index per output feature.
// One 64-lane wave per row of expansion_mapping [OUT_F, IN_F].
__global__ __launch_bounds__(256) void urbf_build_idx(
    const float* __restrict__ em, int* __restrict__ idx) {
    const int wave = blockIdx.x * (blockDim.x >> 6) + (threadIdx.x >> 6);
    const int lane = threadIdx.x & 63;
    if (wave >= OUT_F) return;
    const float* row = em + (size_t)wave * IN_F;
    int found = 0;
    #pragma unroll
    for (int c = 0; c < IN_F; c += 64) {
        const float v = row[c + lane];
        const unsigned long long m = __ballot(v != 0.0f);
        if (m) found = c + (int)(__ffsll((unsigned long long)m) - 1);
    }
    if (lane == 0) idx[wave] = found;
}

// Kernel 2: each thread owns 4 consecutive output features (one float4 of j),
// loads its params ONCE into registers, then streams over B_PER_BLOCK batch
// rows. out[b,j] = exp2(a*(x[b,si]-mu)^2)*cc with a = -0.5*log2(e)/vars^2.
//
// Fast path (uniform across the grid for a one-hot em): j..j+3 share one
// source index, so load x ONCE per row, and batch all 16 row-loads ahead of
// the compute+store loop (16 independent loads in flight per thread).
// Stores are PLAIN (not nontemporal): the 128 MiB output fits the 256 MiB
// Infinity Cache; nt forced the HBM path. Fill-kernel evidence: plain stores
// sustain 6.5 TB/s on this chip.
__global__ __launch_bounds__(256) void urbf_main(
    const float* __restrict__ x, const int* __restrict__ idx,
    const float* __restrict__ means, const float* __restrict__ vars_,
    const float* __restrict__ coefs, float* __restrict__ out) {
    const int j4 = blockIdx.x * 256 + threadIdx.x;   // blockIdx.x in [0,4)
    const int j  = j4 << 2;

    const int4   si = *(const int4*)(idx + j);
    const float4 mu = *(const float4*)(means + j);
    const float4 vv = *(const float4*)(vars_ + j);
    const float4 cc = *(const float4*)(coefs + j);

    // a = -0.5*log2(e) / v^2  (fold the division + exp base-change into one mul)
    const float C = -0.72134752044448170368f;  // -0.5 * log2(e)
    float4 a;
    {
        float4 r;
        r.x = __frcp_rn(vv.x); r.y = __frcp_rn(vv.y);
        r.z = __frcp_rn(vv.z); r.w = __frcp_rn(vv.w);
        a.x = C * r.x * r.x; a.y = C * r.y * r.y;
        a.z = C * r.z * r.z; a.w = C * r.w * r.w;
    }

    const int b0 = blockIdx.y * B_PER_BLOCK;
    float* op = out + (size_t)b0 * OUT_F + j;

    if (si.x == si.y && si.x == si.z && si.x == si.w) {
        // ---- fast path: one source column per thread ----
        const float* xp = x + (size_t)b0 * IN_F + si.x;
        float xs[B_PER_BLOCK];
        #pragma unroll
        for (int r = 0; r < B_PER_BLOCK; ++r) {   // all loads issued up front
            xs[r] = *xp;
            xp += IN_F;
        }
        #pragma unroll
        for (int r = 0; r < B_PER_BLOCK; ++r) {
            const float xv = xs[r];
            v4f o; float d;
            d = xv - mu.x; o.x = __builtin_amdgcn_exp2f(d * d * a.x) * cc.x;
            d = xv - mu.y; o.y = __builtin_amdgcn_exp2f(d * d * a.y) * cc.y;
            d = xv - mu.z; o.z = __builtin_amdgcn_exp2f(d * d * a.z) * cc.z;
            d = xv - mu.w; o.w = __builtin_amdgcn_exp2f(d * d * a.w) * cc.w;
            *(v4f*)op = o;
            op += OUT_F;
        }
    } else {
        // ---- generic path: arbitrary one-hot rows ----
        #pragma unroll 4
        for (int bb = 0; bb < B_PER_BLOCK; ++bb) {
            const float* xrow = x + (size_t)(b0 + bb) * IN_F;
            const float x0 = xrow[si.x];
            const float x1 = xrow[si.y];
            const float x2 = xrow[si.z];
            const float x3 = xrow[si.w];
            v4f o; float d;
            d = x0 - mu.x; o.x = __builtin_amdgcn_exp2f(d * d * a.x) * cc.x;
            d = x1 - mu.y; o.y = __builtin_amdgcn_exp2f(d * d * a.y) * cc.y;
            d = x2 - mu.z; o.z = __builtin_amdgcn_exp2f(d * d * a.z) * cc.z;
            d = x3 - mu.w; o.w = __builtin_amdgcn_exp2f(d * d * a.w) * cc.w;
            *(v4f*)op = o;
            op += OUT_F;
        }
    }
}

extern "C" void kernel_launch(void* const* d_in, const int* in_sizes, int n_in,
                              void* d_out, int out_size, void* d_ws, size_t ws_size,
                              hipStream_t stream) {
    const float* x     = (const float*)d_in[0];   // [BATCH, IN_F]
    const float* em    = (const float*)d_in[1];   // [OUT_F, IN_F]
    const float* means = (const float*)d_in[2];   // [OUT_F]
    const float* vars_ = (const float*)d_in[3];   // [OUT_F]
    const float* coefs = (const float*)d_in[4];   // [OUT_F]
    float* out = (float*)d_out;                   // [BATCH, OUT_F]
    int* idx = (int*)d_ws;                        // 4096 ints = 16 KiB

    // Kernel 1: 4096 waves, 4 waves/block -> 1024 blocks.
    urbf_build_idx<<<OUT_F / 4, 256, 0, stream>>>(em, idx);

    // Kernel 2: grid (j-chunks=4, b-chunks=512), 256 threads.
    dim3 grid(OUT_F / 4 / 256, BATCH / B_PER_BLOCK);
    urbf_main<<<grid, 256, 0, stream>>>(x, idx, means, vars_, coefs, out);
}

// Round 2
// 151.745 us; speedup vs baseline: 1.0814x; 1.0031x over previous
//
#include <hip/hip_runtime.h>

#define IN_F 256
#define OUT_F 4096
#define BATCH 8192
#define ROWS_PER_BLOCK 8   // full 16 KiB rows per block; grid = 1024 blocks

typedef float v4f __attribute__((ext_vector_type(4)));

// Kernel 1: recover the one-hot source index per output feature.
// One 64-lane wave per row of expansion_mapping [OUT_F, IN_F].
// float4 load: the whole 1 KiB row in ONE vector load per wave.
__global__ __launch_bounds__(256) void urbf_build_idx(
    const float* __restrict__ em, int* __restrict__ idx) {
    const int wave = blockIdx.x * (blockDim.x >> 6) + (threadIdx.x >> 6);
    const int lane = threadIdx.x & 63;
    if (wave >= OUT_F) return;
    const float4 v = *(const float4*)(em + (size_t)wave * IN_F + lane * 4);
    const bool nz = (v.x != 0.0f) | (v.y != 0.0f) | (v.z != 0.0f) | (v.w != 0.0f);
    const unsigned long long m = __ballot(nz);
    const int sub = (v.x != 0.0f) ? 0 : (v.y != 0.0f) ? 1 : (v.z != 0.0f) ? 2 : 3;
    const int src = m ? (int)(__ffsll(m) - 1) : 0;
    const int subs = __shfl(sub, src);
    if (lane == 0) idx[wave] = m ? src * 4 + subs : 0;
}

// Kernel 2: one block owns ROWS_PER_BLOCK *full* output rows (contiguous
// 128 KiB region). Each thread owns 4 j-chunks (j = jj*1024 + 4*tid), params
// in registers, and streams 8 rows. Inner structure writes each 16 KiB row
// densely (all 4 waves, all 4 chunks, one tight window), rows consecutive —
// fill-kernel-like DRAM page locality instead of 16 KiB-strided 4 KiB chunks.
__global__ __launch_bounds__(256) void urbf_main(
    const float* __restrict__ x, const int* __restrict__ idx,
    const float* __restrict__ means, const float* __restrict__ vars_,
    const float* __restrict__ coefs, float* __restrict__ out) {
    const int t = threadIdx.x;
    const float C = -0.72134752044448170368f;  // -0.5 * log2(e)

    int    sis[4];
    float4 mu[4], a[4], cc[4];
    bool uniform = true;
    #pragma unroll
    for (int jj = 0; jj < 4; ++jj) {
        const int j = jj * 1024 + t * 4;
        const int4 si = *(const int4*)(idx + j);
        sis[jj] = si.x;
        uniform = uniform & (si.x == si.y) & (si.x == si.z) & (si.x == si.w);
        mu[jj] = *(const float4*)(means + j);
        cc[jj] = *(const float4*)(coefs + j);
        const float4 vv = *(const float4*)(vars_ + j);
        float4 r;
        r.x = __frcp_rn(vv.x); r.y = __frcp_rn(vv.y);
        r.z = __frcp_rn(vv.z); r.w = __frcp_rn(vv.w);
        a[jj].x = C * r.x * r.x; a[jj].y = C * r.y * r.y;
        a[jj].z = C * r.z * r.z; a[jj].w = C * r.w * r.w;
    }

    const int b0 = blockIdx.x * ROWS_PER_BLOCK;
    const float* xb = x + (size_t)b0 * IN_F;
    float* ob = out + (size_t)b0 * OUT_F + t * 4;

    if (uniform) {
        // ---- fast path: one source column per chunk; all 32 loads up front ----
        float xs[ROWS_PER_BLOCK][4];
        #pragma unroll
        for (int r = 0; r < ROWS_PER_BLOCK; ++r) {
            #pragma unroll
            for (int jj = 0; jj < 4; ++jj)
                xs[r][jj] = xb[r * IN_F + sis[jj]];
        }
        #pragma unroll
        for (int r = 0; r < ROWS_PER_BLOCK; ++r) {
            float* op = ob + (size_t)r * OUT_F;
            #pragma unroll
            for (int jj = 0; jj < 4; ++jj) {
                const float xv = xs[r][jj];
                v4f o; float d;
                d = xv - mu[jj].x; o.x = __builtin_amdgcn_exp2f(d * d * a[jj].x) * cc[jj].x;
                d = xv - mu[jj].y; o.y = __builtin_amdgcn_exp2f(d * d * a[jj].y) * cc[jj].y;
                d = xv - mu[jj].z; o.z = __builtin_amdgcn_exp2f(d * d * a[jj].z) * cc[jj].z;
                d = xv - mu[jj].w; o.w = __builtin_amdgcn_exp2f(d * d * a[jj].w) * cc[jj].w;
                *(v4f*)(op + jj * 1024) = o;
            }
        }
    } else {
        // ---- generic path: arbitrary one-hot rows (4 gathers per chunk) ----
        #pragma unroll
        for (int r = 0; r < ROWS_PER_BLOCK; ++r) {
            const float* xrow = xb + (size_t)r * IN_F;
            float* op = ob + (size_t)r * OUT_F;
            #pragma unroll
            for (int jj = 0; jj < 4; ++jj) {
                const int j = jj * 1024 + t * 4;
                const int4 si = *(const int4*)(idx + j);
                v4f o; float d;
                d = xrow[si.x] - mu[jj].x; o.x = __builtin_amdgcn_exp2f(d * d * a[jj].x) * cc[jj].x;
                d = xrow[si.y] - mu[jj].y; o.y = __builtin_amdgcn_exp2f(d * d * a[jj].y) * cc[jj].y;
                d = xrow[si.z] - mu[jj].z; o.z = __builtin_amdgcn_exp2f(d * d * a[jj].z) * cc[jj].z;
                d = xrow[si.w] - mu[jj].w; o.w = __builtin_amdgcn_exp2f(d * d * a[jj].w) * cc[jj].w;
                *(v4f*)(op + jj * 1024) = o;
            }
        }
    }
}

extern "C" void kernel_launch(void* const* d_in, const int* in_sizes, int n_in,
                              void* d_out, int out_size, void* d_ws, size_t ws_size,
                              hipStream_t stream) {
    const float* x     = (const float*)d_in[0];   // [BATCH, IN_F]
    const float* em    = (const float*)d_in[1];   // [OUT_F, IN_F]
    const float* means = (const float*)d_in[2];   // [OUT_F]
    const float* vars_ = (const float*)d_in[3];   // [OUT_F]
    const float* coefs = (const float*)d_in[4];   // [OUT_F]
    float* out = (float*)d_out;                   // [BATCH, OUT_F]
    int* idx = (int*)d_ws;                        // 4096 ints = 16 KiB

    // Kernel 1: 4096 waves, 4 waves/block -> 1024 blocks.
    urbf_build_idx<<<OUT_F / 4, 256, 0, stream>>>(em, idx);

    // Kernel 2: 1024 blocks, each owns 8 full rows (128 KiB contiguous).
    urbf_main<<<BATCH / ROWS_PER_BLOCK, 256, 0, stream>>>(x, idx, means, vars_, coefs, out);
}